// Round 1
// baseline (153.281 us; speedup 1.0000x reference)
//
#include <hip/hip_runtime.h>
#include <hip/hip_cooperative_groups.h>

namespace cg = cooperative_groups;

#define NTH 21
#define NROWS (2 * NTH + 2)   // 42 threshold accumulators + Snu + Sdu = 44
#define NBLK 256              // 1 block/CU; all blocks co-resident for grid.sync
#define THREADS 256
#define EPSF 1e-10f

// ws layout (floats):
//   [PAIRS_OFF_F ..] : float2 pairs[NBLK]          (per-block {min,max}, phase A)
//   [TH_OFF_F ..]    : float th[NTH]               (fallback path only)
//   [PART_OFF_F ..]  : float partials[NROWS][NBLK] (transposed, phase B)
#define PAIRS_OFF_F 16
#define TH_OFF_F 1024
#define PART_OFF_F 2560

static __device__ __forceinline__ float bcast_f(float v) {
  // wave-uniform broadcast -> forces SGPR allocation for thresholds
  // (without this, th[21] lands in VGPRs and the 42 accumulators spill)
  return __uint_as_float(__builtin_amdgcn_readfirstlane(__float_as_uint(v)));
}

// ============================================================================
// Fused single-dispatch cooperative kernel.
// Phase A: grid min/max of unc -> pairs[].          grid.sync()
// Phase B: per-block (redundant) threshold reduce from pairs (2 KB, L2-hot),
//          then the main accumulation loop -> transposed partials.
//                                                    grid.sync()
// Phase C: block 0 reduces partials, computes AUC, writes out[0..1].
// ============================================================================
__global__ void __launch_bounds__(THREADS) fused_kernel(
    const float4* __restrict__ probs4,
    const int4* __restrict__ labels4,
    const float4* __restrict__ unc4,
    float* __restrict__ ws,
    float* __restrict__ out,
    int n4) {
  cg::grid_group grid = cg::this_grid();
  const int t = threadIdx.x;
  const int b = blockIdx.x;
  const int lane = t & 63, wv = t >> 6;

  __shared__ float smin[4], smax[4];
  __shared__ float summ[2];
  __shared__ float lred[4][NROWS];

  // ---------------- Phase A: grid-wide min/max of unc ----------------
  {
    float lmin = 1e30f, lmax = -1e30f;
    int stride = NBLK * THREADS;
    for (int i = b * THREADS + t; i < n4; i += stride) {
      float4 v = unc4[i];
      lmin = fminf(lmin, fminf(fminf(v.x, v.y), fminf(v.z, v.w)));
      lmax = fmaxf(lmax, fmaxf(fmaxf(v.x, v.y), fmaxf(v.z, v.w)));
    }
    #pragma unroll
    for (int off = 32; off > 0; off >>= 1) {
      lmin = fminf(lmin, __shfl_down(lmin, off));
      lmax = fmaxf(lmax, __shfl_down(lmax, off));
    }
    if (lane == 0) { smin[wv] = lmin; smax[wv] = lmax; }
    __syncthreads();
    if (t == 0) {
      float bmin = fminf(fminf(smin[0], smin[1]), fminf(smin[2], smin[3]));
      float bmax = fmaxf(fmaxf(smax[0], smax[1]), fmaxf(smax[2], smax[3]));
      ((float2*)(ws + PAIRS_OFF_F))[b] = make_float2(bmin, bmax);
    }
  }

  grid.sync();   // pairs[] visible everywhere (release/acquire across XCDs)

  // ------- Phase B1: per-block threshold compute (redundant, cheap) -------
  float th[NTH];
  {
    float2 v = ((const float2*)(ws + PAIRS_OFF_F))[t];  // t < NBLK == THREADS
    float gmin = v.x, gmax = v.y;
    #pragma unroll
    for (int off = 32; off > 0; off >>= 1) {
      gmin = fminf(gmin, __shfl_down(gmin, off));
      gmax = fmaxf(gmax, __shfl_down(gmax, off));
    }
    if (lane == 0) { smin[wv] = gmin; smax[wv] = gmax; }
    __syncthreads();
    if (t == 0) {
      float umin = fminf(fminf(smin[0], smin[1]), fminf(smin[2], smin[3]));
      float umax = fmaxf(fmaxf(smax[0], smax[1]), fmaxf(smax[2], smax[3]));
      summ[0] = umin;
      summ[1] = umax - umin;
    }
    __syncthreads();
    // same-address LDS broadcast, then force into SGPRs (bitwise-identical
    // th[] in every block: same inputs, same op order as old thresh_kernel)
    float umin = bcast_f(summ[0]);
    float r = bcast_f(summ[1]);
    #pragma unroll
    for (int j = 0; j < NTH; ++j) th[j] = umin + ((float)j * 0.05f) * r;
  }

  // ---------------- Phase B2: main accumulation (unchanged) ----------------
  float accn[NTH], accd[NTH];
  #pragma unroll
  for (int j = 0; j < NTH; ++j) { accn[j] = 0.f; accd[j] = 0.f; }
  float Snu = 0.f, Sdu = 0.f;

  int stride = NBLK * THREADS;
  for (int i4 = b * THREADS + t; i4 < n4; i4 += stride) {
    float4 u4 = unc4[i4];
    float4 pA = probs4[2 * (size_t)i4];
    float4 pB = probs4[2 * (size_t)i4 + 1];
    int4 lb = labels4[i4];
    float us[4] = {u4.x, u4.y, u4.z, u4.w};
    float pxs[4] = {pA.x, pA.z, pB.x, pB.z};
    float pys[4] = {pA.y, pA.w, pB.y, pB.w};
    int labs[4] = {lb.x, lb.y, lb.z, lb.w};
    #pragma unroll
    for (int e = 0; e < 4; ++e) {
      float u = us[e];
      float conf = pys[e];
      int pred = (pys[e] > pxs[e]) ? 1 : 0;   // argmax: index 0 wins ties
      bool accb = (labs[e] == pred);
      float ex = __expf(2.0f * u);
      float tt = 1.0f - 2.0f / (1.0f + ex);   // tanh(u)
      float w1 = accb ? conf : (1.0f - conf);
      float du_ = w1 * tt;                    // uncertain-side weight
      float dc = w1 - du_;                    // certain-side weight
      float dd = dc - du_;                    // den delta when certain
      float dn = accb ? dc : -du_;            // num delta when certain
      float nu = accb ? 0.f : du_;            // num base (uncertain)
      Snu += nu;
      Sdu += du_;
      #pragma unroll
      for (int j = 0; j < NTH; ++j) {
        float cf = (u <= th[j]) ? 1.0f : 0.0f;
        accn[j] += cf * dn;
        accd[j] += cf * dd;
      }
    }
  }

  // ---- block combine: shfl + LDS, write transposed partials ----
  float* partials = ws + PART_OFF_F;
  #pragma unroll
  for (int v = 0; v < NTH; ++v) {
    float x = accn[v], y = accd[v];
    #pragma unroll
    for (int off = 32; off > 0; off >>= 1) {
      x += __shfl_down(x, off);
      y += __shfl_down(y, off);
    }
    if (lane == 0) { lred[wv][v] = x; lred[wv][NTH + v] = y; }
  }
  {
    float x = Snu, y = Sdu;
    #pragma unroll
    for (int off = 32; off > 0; off >>= 1) {
      x += __shfl_down(x, off);
      y += __shfl_down(y, off);
    }
    if (lane == 0) { lred[wv][2 * NTH] = x; lred[wv][2 * NTH + 1] = y; }
  }
  __syncthreads();
  if (t < NROWS) {
    float s = lred[0][t] + lred[1][t] + lred[2][t] + lred[3][t];
    partials[(size_t)t * NBLK + b] = s;
  }

  grid.sync();   // partials[] visible to block 0

  // ---------------- Phase C: block 0 final reduction ----------------
  if (b == 0) {
    // same summation order as the old final_kernel: 16 chunks x 16 floats
    __shared__ float lds2[NROWS][16];
    __shared__ float hh[NROWS];
    for (int slot = t; slot < NROWS * 16; slot += THREADS) {
      int row = slot >> 4, ch = slot & 15;
      const float4* p4 =
          (const float4*)(partials + (size_t)row * NBLK + ch * 16);
      float s = 0.f;
      #pragma unroll
      for (int m = 0; m < 4; ++m) {
        float4 v = p4[m];
        s += (v.x + v.y) + (v.z + v.w);
      }
      lds2[row][ch] = s;
    }
    __syncthreads();
    if (t < NROWS) {
      float s = 0.f;
      #pragma unroll
      for (int c = 0; c < 16; ++c) s += lds2[t][c];
      hh[t] = s;
    }
    __syncthreads();
    if (t == 0) {
      float SnuT = hh[2 * NTH], SduT = hh[2 * NTH + 1];
      float auc = 0.f, prev = 0.f;
      #pragma unroll
      for (int j = 0; j < NTH; ++j) {
        float num = SnuT + hh[j];
        float den = SduT + hh[NTH + j];
        float avu = num / (den + EPSF);
        if (j > 0) auc += 0.5f * (avu + prev) * 0.05f;
        prev = avu;
      }
      out[0] = -logf(auc + EPSF);   // BETA = 1
      out[1] = auc;
    }
  }
}

// ============================================================================
// Fallback path (proven 4-kernel pipeline) — used only if the cooperative
// launch is rejected (e.g. unsupported under graph capture).
// ============================================================================
__global__ void __launch_bounds__(THREADS) minmax_kernel(
    const float4* __restrict__ unc4, float* __restrict__ ws, int n4) {
  float lmin = 1e30f, lmax = -1e30f;
  int stride = gridDim.x * blockDim.x;
  for (int i = blockIdx.x * blockDim.x + threadIdx.x; i < n4; i += stride) {
    float4 v = unc4[i];
    lmin = fminf(lmin, fminf(fminf(v.x, v.y), fminf(v.z, v.w)));
    lmax = fmaxf(lmax, fmaxf(fmaxf(v.x, v.y), fmaxf(v.z, v.w)));
  }
  #pragma unroll
  for (int off = 32; off > 0; off >>= 1) {
    lmin = fminf(lmin, __shfl_down(lmin, off));
    lmax = fmaxf(lmax, __shfl_down(lmax, off));
  }
  __shared__ float smin[4], smax[4];
  int wv = threadIdx.x >> 6;
  if ((threadIdx.x & 63) == 0) { smin[wv] = lmin; smax[wv] = lmax; }
  __syncthreads();
  if (threadIdx.x == 0) {
    float bmin = fminf(fminf(smin[0], smin[1]), fminf(smin[2], smin[3]));
    float bmax = fmaxf(fmaxf(smax[0], smax[1]), fmaxf(smax[2], smax[3]));
    ((float2*)(ws + PAIRS_OFF_F))[blockIdx.x] = make_float2(bmin, bmax);
  }
}

__global__ void __launch_bounds__(THREADS) thresh_kernel(float* __restrict__ ws) {
  int t = threadIdx.x;
  float2 v = ((const float2*)(ws + PAIRS_OFF_F))[t];
  float gmin = v.x, gmax = v.y;
  #pragma unroll
  for (int off = 32; off > 0; off >>= 1) {
    gmin = fminf(gmin, __shfl_down(gmin, off));
    gmax = fmaxf(gmax, __shfl_down(gmax, off));
  }
  __shared__ float smin[4], smax[4];
  int wv = t >> 6;
  if ((t & 63) == 0) { smin[wv] = gmin; smax[wv] = gmax; }
  __syncthreads();
  if (t == 0) {
    float umin = fminf(fminf(smin[0], smin[1]), fminf(smin[2], smin[3]));
    float umax = fmaxf(fmaxf(smax[0], smax[1]), fmaxf(smax[2], smax[3]));
    float r = umax - umin;
    #pragma unroll
    for (int j = 0; j < NTH; ++j)
      ws[TH_OFF_F + j] = umin + ((float)j * 0.05f) * r;
  }
}

__global__ void __launch_bounds__(THREADS) main_kernel(
    const float4* __restrict__ probs4,
    const int4* __restrict__ labels4,
    const float4* __restrict__ unc4,
    float* __restrict__ ws, int n4) {
  const int t = threadIdx.x;
  const int b = blockIdx.x;
  const int lane = t & 63, wv = t >> 6;

  __shared__ float lred[4][NROWS];

  float th[NTH];
  #pragma unroll
  for (int j = 0; j < NTH; ++j) th[j] = bcast_f(ws[TH_OFF_F + j]);

  float accn[NTH], accd[NTH];
  #pragma unroll
  for (int j = 0; j < NTH; ++j) { accn[j] = 0.f; accd[j] = 0.f; }
  float Snu = 0.f, Sdu = 0.f;

  int stride = NBLK * THREADS;
  for (int i4 = b * THREADS + t; i4 < n4; i4 += stride) {
    float4 u4 = unc4[i4];
    float4 pA = probs4[2 * (size_t)i4];
    float4 pB = probs4[2 * (size_t)i4 + 1];
    int4 lb = labels4[i4];
    float us[4] = {u4.x, u4.y, u4.z, u4.w};
    float pxs[4] = {pA.x, pA.z, pB.x, pB.z};
    float pys[4] = {pA.y, pA.w, pB.y, pB.w};
    int labs[4] = {lb.x, lb.y, lb.z, lb.w};
    #pragma unroll
    for (int e = 0; e < 4; ++e) {
      float u = us[e];
      float conf = pys[e];
      int pred = (pys[e] > pxs[e]) ? 1 : 0;
      bool accb = (labs[e] == pred);
      float ex = __expf(2.0f * u);
      float tt = 1.0f - 2.0f / (1.0f + ex);
      float w1 = accb ? conf : (1.0f - conf);
      float du_ = w1 * tt;
      float dc = w1 - du_;
      float dd = dc - du_;
      float dn = accb ? dc : -du_;
      float nu = accb ? 0.f : du_;
      Snu += nu;
      Sdu += du_;
      #pragma unroll
      for (int j = 0; j < NTH; ++j) {
        float cf = (u <= th[j]) ? 1.0f : 0.0f;
        accn[j] += cf * dn;
        accd[j] += cf * dd;
      }
    }
  }

  float* partials = ws + PART_OFF_F;
  #pragma unroll
  for (int v = 0; v < NTH; ++v) {
    float x = accn[v], y = accd[v];
    #pragma unroll
    for (int off = 32; off > 0; off >>= 1) {
      x += __shfl_down(x, off);
      y += __shfl_down(y, off);
    }
    if (lane == 0) { lred[wv][v] = x; lred[wv][NTH + v] = y; }
  }
  {
    float x = Snu, y = Sdu;
    #pragma unroll
    for (int off = 32; off > 0; off >>= 1) {
      x += __shfl_down(x, off);
      y += __shfl_down(y, off);
    }
    if (lane == 0) { lred[wv][2 * NTH] = x; lred[wv][2 * NTH + 1] = y; }
  }
  __syncthreads();
  if (t < NROWS) {
    float s = lred[0][t] + lred[1][t] + lred[2][t] + lred[3][t];
    partials[(size_t)t * NBLK + b] = s;
  }
}

__global__ void final_kernel(const float* __restrict__ ws,
                             float* __restrict__ out) {
  const float* partials = ws + PART_OFF_F;
  __shared__ float lds[NROWS][16];
  __shared__ float hh[NROWS];
  int t = threadIdx.x;
  if (t < NROWS * 16) {
    int row = t >> 4, ch = t & 15;
    const float4* p4 = (const float4*)(partials + (size_t)row * NBLK + ch * 16);
    float s = 0.f;
    #pragma unroll
    for (int m = 0; m < 4; ++m) {
      float4 v = p4[m];
      s += (v.x + v.y) + (v.z + v.w);
    }
    lds[row][ch] = s;
  }
  __syncthreads();
  if (t < NROWS) {
    float s = 0.f;
    #pragma unroll
    for (int c = 0; c < 16; ++c) s += lds[t][c];
    hh[t] = s;
  }
  __syncthreads();
  if (t == 0) {
    float SnuT = hh[2 * NTH], SduT = hh[2 * NTH + 1];
    float auc = 0.f, prev = 0.f;
    #pragma unroll
    for (int j = 0; j < NTH; ++j) {
      float num = SnuT + hh[j];
      float den = SduT + hh[NTH + j];
      float avu = num / (den + EPSF);
      if (j > 0) auc += 0.5f * (avu + prev) * 0.05f;
      prev = avu;
    }
    out[0] = -logf(auc + EPSF);
    out[1] = auc;
  }
}

extern "C" void kernel_launch(void* const* d_in, const int* in_sizes, int n_in,
                              void* d_out, int out_size, void* d_ws, size_t ws_size,
                              hipStream_t stream) {
  const float4* probs4 = (const float4*)d_in[0];
  const int4* labels4 = (const int4*)d_in[1];
  const float4* unc4 = (const float4*)d_in[2];
  float* wsf = (float*)d_ws;
  float* outf = (float*)d_out;
  int n4 = in_sizes[2] / 4;

  void* args[6];
  args[0] = (void*)&probs4;
  args[1] = (void*)&labels4;
  args[2] = (void*)&unc4;
  args[3] = (void*)&wsf;
  args[4] = (void*)&outf;
  args[5] = (void*)&n4;

  hipError_t err = hipLaunchCooperativeKernel(
      reinterpret_cast<void*>(fused_kernel), dim3(NBLK), dim3(THREADS),
      args, 0, stream);

  if (err != hipSuccess) {
    // fallback: proven 4-kernel pipeline (coherence via kernel boundaries)
    minmax_kernel<<<NBLK, THREADS, 0, stream>>>(unc4, wsf, n4);
    thresh_kernel<<<1, THREADS, 0, stream>>>(wsf);
    main_kernel<<<NBLK, THREADS, 0, stream>>>(probs4, labels4, unc4, wsf, n4);
    final_kernel<<<1, NROWS * 16, 0, stream>>>(wsf, (float*)d_out);
  }
}

// Round 2
// 94.678 us; speedup vs baseline: 1.6190x; 1.6190x over previous
//
#include <hip/hip_runtime.h>

#define NTH 21
#define NROWS (2 * NTH + 2)   // 42 threshold accumulators + Snu + Sdu = 44
#define NBLK 256              // 1 block/CU (grid); co-residency not required
#define TMAIN 1024            // 16 waves/block = 4 waves/SIMD (latency hiding)
#define TMM 1024
#define EPSF 1e-10f

// ws layout (floats):
//   [PAIRS_OFF_F ..] : float2 pairs[NBLK]          (per-block {min,max} from K1)
//   [PART_OFF_F ..]  : float partials[NROWS][NBLK] (transposed, from K2)
// Coherence purely via kernel boundaries:
//   R1 measured grid.sync() at ~30us each (cross-XCD spin) -> cooperative path
//   abandoned. Prior session: fences +115us, global atomics +11us. Boundaries win.
#define PAIRS_OFF_F 16
#define PART_OFF_F 2560

static __device__ __forceinline__ float bcast_f(float v) {
  // wave-uniform broadcast -> forces SGPR allocation for thresholds
  // (without this, th[21] lands in VGPRs and the 42 accumulators spill)
  return __uint_as_float(__builtin_amdgcn_readfirstlane(__float_as_uint(v)));
}

// K1: grid min/max of unc -> per-block pairs. min/max are order-exact, so any
// thread/block config gives bitwise-identical results.
__global__ void __launch_bounds__(TMM) minmax_kernel(
    const float4* __restrict__ unc4, float* __restrict__ ws, int n4) {
  float lmin = 1e30f, lmax = -1e30f;
  int stride = gridDim.x * blockDim.x;
  for (int i = blockIdx.x * blockDim.x + threadIdx.x; i < n4; i += stride) {
    float4 v = unc4[i];
    lmin = fminf(lmin, fminf(fminf(v.x, v.y), fminf(v.z, v.w)));
    lmax = fmaxf(lmax, fmaxf(fmaxf(v.x, v.y), fmaxf(v.z, v.w)));
  }
  #pragma unroll
  for (int off = 32; off > 0; off >>= 1) {
    lmin = fminf(lmin, __shfl_down(lmin, off));
    lmax = fmaxf(lmax, __shfl_down(lmax, off));
  }
  __shared__ float smin[TMM / 64], smax[TMM / 64];
  int wv = threadIdx.x >> 6;
  if ((threadIdx.x & 63) == 0) { smin[wv] = lmin; smax[wv] = lmax; }
  __syncthreads();
  if (threadIdx.x == 0) {
    float bmin = smin[0], bmax = smax[0];
    #pragma unroll
    for (int w = 1; w < TMM / 64; ++w) {
      bmin = fminf(bmin, smin[w]);
      bmax = fmaxf(bmax, smax[w]);
    }
    ((float2*)(ws + PAIRS_OFF_F))[blockIdx.x] = make_float2(bmin, bmax);
  }
}

// K2: per-block redundant threshold reduce (pairs are 2 KB, L2/L3-hot) + main
// accumulation. th[] is bitwise identical to the old thresh_kernel: min/max
// over duplicated values in any order is exact, and the th formula is unchanged.
__global__ void __launch_bounds__(TMAIN) main_kernel(
    const float4* __restrict__ probs4,
    const int4* __restrict__ labels4,
    const float4* __restrict__ unc4,
    float* __restrict__ ws, int n4) {
  const int t = threadIdx.x;
  const int b = blockIdx.x;
  const int lane = t & 63, wv = t >> 6;
  const int NWV = TMAIN / 64;

  __shared__ float smin[NWV], smax[NWV];
  __shared__ float summ[2];
  __shared__ float lred[NWV][NROWS];

  // ---- thresholds from pairs (redundant per block; duplicates are harmless
  //      for min/max) ----
  float th[NTH];
  {
    float2 v = ((const float2*)(ws + PAIRS_OFF_F))[t & (NBLK - 1)];
    float gmin = v.x, gmax = v.y;
    #pragma unroll
    for (int off = 32; off > 0; off >>= 1) {
      gmin = fminf(gmin, __shfl_down(gmin, off));
      gmax = fmaxf(gmax, __shfl_down(gmax, off));
    }
    if (lane == 0) { smin[wv] = gmin; smax[wv] = gmax; }
    __syncthreads();
    if (t == 0) {
      float umin = smin[0], umax = smax[0];
      #pragma unroll
      for (int w = 1; w < NWV; ++w) {
        umin = fminf(umin, smin[w]);
        umax = fmaxf(umax, smax[w]);
      }
      summ[0] = umin;
      summ[1] = umax - umin;
    }
    __syncthreads();
    // same-address LDS broadcast, then force into SGPRs
    float umin = bcast_f(summ[0]);
    float r = bcast_f(summ[1]);
    #pragma unroll
    for (int j = 0; j < NTH; ++j) th[j] = umin + ((float)j * 0.05f) * r;
  }

  // ---- main accumulation (element math unchanged) ----
  float accn[NTH], accd[NTH];
  #pragma unroll
  for (int j = 0; j < NTH; ++j) { accn[j] = 0.f; accd[j] = 0.f; }
  float Snu = 0.f, Sdu = 0.f;

  int stride = NBLK * TMAIN;
  for (int i4 = b * TMAIN + t; i4 < n4; i4 += stride) {
    float4 u4 = unc4[i4];
    float4 pA = probs4[2 * (size_t)i4];
    float4 pB = probs4[2 * (size_t)i4 + 1];
    int4 lb = labels4[i4];
    float us[4] = {u4.x, u4.y, u4.z, u4.w};
    float pxs[4] = {pA.x, pA.z, pB.x, pB.z};
    float pys[4] = {pA.y, pA.w, pB.y, pB.w};
    int labs[4] = {lb.x, lb.y, lb.z, lb.w};
    #pragma unroll
    for (int e = 0; e < 4; ++e) {
      float u = us[e];
      float conf = pys[e];
      int pred = (pys[e] > pxs[e]) ? 1 : 0;   // argmax: index 0 wins ties
      bool accb = (labs[e] == pred);
      float ex = __expf(2.0f * u);
      float tt = 1.0f - 2.0f / (1.0f + ex);   // tanh(u)
      float w1 = accb ? conf : (1.0f - conf);
      float du_ = w1 * tt;                    // uncertain-side weight
      float dc = w1 - du_;                    // certain-side weight
      float dd = dc - du_;                    // den delta when certain
      float dn = accb ? dc : -du_;            // num delta when certain
      float nu = accb ? 0.f : du_;            // num base (uncertain)
      Snu += nu;
      Sdu += du_;
      #pragma unroll
      for (int j = 0; j < NTH; ++j) {
        float cf = (u <= th[j]) ? 1.0f : 0.0f;
        accn[j] += cf * dn;
        accd[j] += cf * dd;
      }
    }
  }

  // ---- block combine: shfl + LDS, write transposed partials ----
  float* partials = ws + PART_OFF_F;
  #pragma unroll
  for (int v = 0; v < NTH; ++v) {
    float x = accn[v], y = accd[v];
    #pragma unroll
    for (int off = 32; off > 0; off >>= 1) {
      x += __shfl_down(x, off);
      y += __shfl_down(y, off);
    }
    if (lane == 0) { lred[wv][v] = x; lred[wv][NTH + v] = y; }
  }
  {
    float x = Snu, y = Sdu;
    #pragma unroll
    for (int off = 32; off > 0; off >>= 1) {
      x += __shfl_down(x, off);
      y += __shfl_down(y, off);
    }
    if (lane == 0) { lred[wv][2 * NTH] = x; lred[wv][2 * NTH + 1] = y; }
  }
  __syncthreads();
  if (t < NROWS) {
    float s = lred[0][t];
    #pragma unroll
    for (int w = 1; w < NWV; ++w) s += lred[w][t];
    partials[(size_t)t * NBLK + b] = s;
  }
}

// K3: one block: 44 rows x 16 chunks = 704 threads; each sums 16 floats
__global__ void final_kernel(const float* __restrict__ ws,
                             float* __restrict__ out) {
  const float* partials = ws + PART_OFF_F;
  __shared__ float lds[NROWS][16];
  __shared__ float hh[NROWS];
  int t = threadIdx.x;
  if (t < NROWS * 16) {
    int row = t >> 4, ch = t & 15;
    const float4* p4 = (const float4*)(partials + (size_t)row * NBLK + ch * 16);
    float s = 0.f;
    #pragma unroll
    for (int m = 0; m < 4; ++m) {
      float4 v = p4[m];
      s += (v.x + v.y) + (v.z + v.w);
    }
    lds[row][ch] = s;
  }
  __syncthreads();
  if (t < NROWS) {
    float s = 0.f;
    #pragma unroll
    for (int c = 0; c < 16; ++c) s += lds[t][c];
    hh[t] = s;
  }
  __syncthreads();
  if (t == 0) {
    float SnuT = hh[2 * NTH], SduT = hh[2 * NTH + 1];
    float auc = 0.f, prev = 0.f;
    #pragma unroll
    for (int j = 0; j < NTH; ++j) {
      float num = SnuT + hh[j];
      float den = SduT + hh[NTH + j];
      float avu = num / (den + EPSF);
      if (j > 0) auc += 0.5f * (avu + prev) * 0.05f;
      prev = avu;
    }
    out[0] = -logf(auc + EPSF);   // BETA = 1
    out[1] = auc;
  }
}

extern "C" void kernel_launch(void* const* d_in, const int* in_sizes, int n_in,
                              void* d_out, int out_size, void* d_ws, size_t ws_size,
                              hipStream_t stream) {
  const float4* probs4 = (const float4*)d_in[0];
  const int4* labels4 = (const int4*)d_in[1];
  const float4* unc4 = (const float4*)d_in[2];
  float* wsf = (float*)d_ws;
  int n4 = in_sizes[2] / 4;

  minmax_kernel<<<NBLK, TMM, 0, stream>>>(unc4, wsf, n4);
  main_kernel<<<NBLK, TMAIN, 0, stream>>>(probs4, labels4, unc4, wsf, n4);
  final_kernel<<<1, NROWS * 16, 0, stream>>>(wsf, (float*)d_out);
}

// Round 3
// 94.060 us; speedup vs baseline: 1.6296x; 1.0066x over previous
//
#include <hip/hip_runtime.h>

#define NTH 21
#define NROWS (2 * NTH + 2)   // 42 threshold accumulators + Snu + Sdu = 44
#define NBLK 256              // 1 block/CU: best-measured config
#define THREADS 256           // R2 showed 1024 is not better (94.7 vs 91.8)
#define EPSF 1e-10f

// ws layout (floats):
//   [PAIRS_OFF_F ..] : float2 pairs[NBLK]          (per-block {min,max} from K1)
//   [PART_OFF_F ..]  : float partials[NROWS][NBLK] (transposed, from K2)
// Coherence purely via kernel boundaries:
//   R1 measured grid.sync() at ~30us each (cross-XCD spin) -> cooperative dead.
//   Prior session: fences +115us, global atomics +11us. Boundaries win.
// Structure: 3 dispatches. thresh_kernel folded into main_kernel as a
// redundant per-block reduce of pairs[] (2 KB, L2-hot; min/max over
// duplicates is exact -> th[] bitwise identical). Verified in R1/R2.
#define PAIRS_OFF_F 16
#define PART_OFF_F 2560

static __device__ __forceinline__ float bcast_f(float v) {
  // wave-uniform broadcast -> forces SGPR allocation for thresholds
  // (without this, th[21] lands in VGPRs and the 42 accumulators spill)
  return __uint_as_float(__builtin_amdgcn_readfirstlane(__float_as_uint(v)));
}

// K1: grid min/max of unc -> per-block pairs.
__global__ void __launch_bounds__(THREADS) minmax_kernel(
    const float4* __restrict__ unc4, float* __restrict__ ws, int n4) {
  float lmin = 1e30f, lmax = -1e30f;
  int stride = gridDim.x * blockDim.x;
  for (int i = blockIdx.x * blockDim.x + threadIdx.x; i < n4; i += stride) {
    float4 v = unc4[i];
    lmin = fminf(lmin, fminf(fminf(v.x, v.y), fminf(v.z, v.w)));
    lmax = fmaxf(lmax, fmaxf(fmaxf(v.x, v.y), fmaxf(v.z, v.w)));
  }
  #pragma unroll
  for (int off = 32; off > 0; off >>= 1) {
    lmin = fminf(lmin, __shfl_down(lmin, off));
    lmax = fmaxf(lmax, __shfl_down(lmax, off));
  }
  __shared__ float smin[4], smax[4];
  int wv = threadIdx.x >> 6;
  if ((threadIdx.x & 63) == 0) { smin[wv] = lmin; smax[wv] = lmax; }
  __syncthreads();
  if (threadIdx.x == 0) {
    float bmin = fminf(fminf(smin[0], smin[1]), fminf(smin[2], smin[3]));
    float bmax = fmaxf(fmaxf(smax[0], smax[1]), fmaxf(smax[2], smax[3]));
    ((float2*)(ws + PAIRS_OFF_F))[blockIdx.x] = make_float2(bmin, bmax);
  }
}

// K2: per-block redundant threshold reduce + main accumulation.
__global__ void __launch_bounds__(THREADS) main_kernel(
    const float4* __restrict__ probs4,
    const int4* __restrict__ labels4,
    const float4* __restrict__ unc4,
    float* __restrict__ ws, int n4) {
  const int t = threadIdx.x;
  const int b = blockIdx.x;
  const int lane = t & 63, wv = t >> 6;

  __shared__ float smin[4], smax[4];
  __shared__ float summ[2];
  __shared__ float lred[4][NROWS];

  // ---- thresholds from pairs (t spans exactly 0..NBLK-1) ----
  float th[NTH];
  {
    float2 v = ((const float2*)(ws + PAIRS_OFF_F))[t];
    float gmin = v.x, gmax = v.y;
    #pragma unroll
    for (int off = 32; off > 0; off >>= 1) {
      gmin = fminf(gmin, __shfl_down(gmin, off));
      gmax = fmaxf(gmax, __shfl_down(gmax, off));
    }
    if (lane == 0) { smin[wv] = gmin; smax[wv] = gmax; }
    __syncthreads();
    if (t == 0) {
      float umin = fminf(fminf(smin[0], smin[1]), fminf(smin[2], smin[3]));
      float umax = fmaxf(fmaxf(smax[0], smax[1]), fmaxf(smax[2], smax[3]));
      summ[0] = umin;
      summ[1] = umax - umin;
    }
    __syncthreads();
    // same-address LDS broadcast, then force into SGPRs
    float umin = bcast_f(summ[0]);
    float r = bcast_f(summ[1]);
    #pragma unroll
    for (int j = 0; j < NTH; ++j) th[j] = umin + ((float)j * 0.05f) * r;
  }

  // ---- main accumulation (element math unchanged since baseline) ----
  float accn[NTH], accd[NTH];
  #pragma unroll
  for (int j = 0; j < NTH; ++j) { accn[j] = 0.f; accd[j] = 0.f; }
  float Snu = 0.f, Sdu = 0.f;

  int stride = NBLK * THREADS;
  for (int i4 = b * THREADS + t; i4 < n4; i4 += stride) {
    float4 u4 = unc4[i4];
    float4 pA = probs4[2 * (size_t)i4];
    float4 pB = probs4[2 * (size_t)i4 + 1];
    int4 lb = labels4[i4];
    float us[4] = {u4.x, u4.y, u4.z, u4.w};
    float pxs[4] = {pA.x, pA.z, pB.x, pB.z};
    float pys[4] = {pA.y, pA.w, pB.y, pB.w};
    int labs[4] = {lb.x, lb.y, lb.z, lb.w};
    #pragma unroll
    for (int e = 0; e < 4; ++e) {
      float u = us[e];
      float conf = pys[e];
      int pred = (pys[e] > pxs[e]) ? 1 : 0;   // argmax: index 0 wins ties
      bool accb = (labs[e] == pred);
      float ex = __expf(2.0f * u);
      float tt = 1.0f - 2.0f / (1.0f + ex);   // tanh(u)
      float w1 = accb ? conf : (1.0f - conf);
      float du_ = w1 * tt;                    // uncertain-side weight
      float dc = w1 - du_;                    // certain-side weight
      float dd = dc - du_;                    // den delta when certain
      float dn = accb ? dc : -du_;            // num delta when certain
      float nu = accb ? 0.f : du_;            // num base (uncertain)
      Snu += nu;
      Sdu += du_;
      #pragma unroll
      for (int j = 0; j < NTH; ++j) {
        float cf = (u <= th[j]) ? 1.0f : 0.0f;
        accn[j] += cf * dn;
        accd[j] += cf * dd;
      }
    }
  }

  // ---- block combine: shfl + LDS, write transposed partials ----
  float* partials = ws + PART_OFF_F;
  #pragma unroll
  for (int v = 0; v < NTH; ++v) {
    float x = accn[v], y = accd[v];
    #pragma unroll
    for (int off = 32; off > 0; off >>= 1) {
      x += __shfl_down(x, off);
      y += __shfl_down(y, off);
    }
    if (lane == 0) { lred[wv][v] = x; lred[wv][NTH + v] = y; }
  }
  {
    float x = Snu, y = Sdu;
    #pragma unroll
    for (int off = 32; off > 0; off >>= 1) {
      x += __shfl_down(x, off);
      y += __shfl_down(y, off);
    }
    if (lane == 0) { lred[wv][2 * NTH] = x; lred[wv][2 * NTH + 1] = y; }
  }
  __syncthreads();
  if (t < NROWS) {
    float s = lred[0][t] + lred[1][t] + lred[2][t] + lred[3][t];
    partials[(size_t)t * NBLK + b] = s;
  }
}

// K3: one block: 44 rows x 16 chunks = 704 threads; each sums 16 floats
__global__ void final_kernel(const float* __restrict__ ws,
                             float* __restrict__ out) {
  const float* partials = ws + PART_OFF_F;
  __shared__ float lds[NROWS][16];
  __shared__ float hh[NROWS];
  int t = threadIdx.x;
  if (t < NROWS * 16) {
    int row = t >> 4, ch = t & 15;
    const float4* p4 = (const float4*)(partials + (size_t)row * NBLK + ch * 16);
    float s = 0.f;
    #pragma unroll
    for (int m = 0; m < 4; ++m) {
      float4 v = p4[m];
      s += (v.x + v.y) + (v.z + v.w);
    }
    lds[row][ch] = s;
  }
  __syncthreads();
  if (t < NROWS) {
    float s = 0.f;
    #pragma unroll
    for (int c = 0; c < 16; ++c) s += lds[t][c];
    hh[t] = s;
  }
  __syncthreads();
  if (t == 0) {
    float SnuT = hh[2 * NTH], SduT = hh[2 * NTH + 1];
    float auc = 0.f, prev = 0.f;
    #pragma unroll
    for (int j = 0; j < NTH; ++j) {
      float num = SnuT + hh[j];
      float den = SduT + hh[NTH + j];
      float avu = num / (den + EPSF);
      if (j > 0) auc += 0.5f * (avu + prev) * 0.05f;
      prev = avu;
    }
    out[0] = -logf(auc + EPSF);   // BETA = 1
    out[1] = auc;
  }
}

extern "C" void kernel_launch(void* const* d_in, const int* in_sizes, int n_in,
                              void* d_out, int out_size, void* d_ws, size_t ws_size,
                              hipStream_t stream) {
  const float4* probs4 = (const float4*)d_in[0];
  const int4* labels4 = (const int4*)d_in[1];
  const float4* unc4 = (const float4*)d_in[2];
  float* wsf = (float*)d_ws;
  int n4 = in_sizes[2] / 4;

  minmax_kernel<<<NBLK, THREADS, 0, stream>>>(unc4, wsf, n4);
  main_kernel<<<NBLK, THREADS, 0, stream>>>(probs4, labels4, unc4, wsf, n4);
  final_kernel<<<1, NROWS * 16, 0, stream>>>(wsf, (float*)d_out);
}